// Round 5
// baseline (137.519 us; speedup 1.0000x reference)
//
#include <hip/hip_runtime.h>

#define NCLS 64
#define TDIM 512
#define PD   8   // prefetch depth (ring of logit rows)

typedef _Float16 h2 __attribute__((ext_vector_type(2)));

#if __has_builtin(__builtin_amdgcn_fdot2)
#define FDOT2(a, b, c) __builtin_amdgcn_fdot2((a), (b), (c), false)
#else
static __device__ __forceinline__ float FDOT2(h2 a, h2 b, float c) {
    return fmaf((float)a.x, (float)b.x, fmaf((float)a.y, (float)b.y, c));
}
#endif

static __device__ __forceinline__ h2 BC_H2(unsigned x) { return __builtin_bit_cast(h2, x); }

template <int CTRL>
static __device__ __forceinline__ unsigned DPPMOV(unsigned v) {
    return (unsigned)__builtin_amdgcn_update_dpp(0, (int)v, CTRL, 0xf, 0xf, true);
}

// Exchange across the 16-lane-group boundary (lanes i <-> i^16).
// Returns the pair {x, y} = {own, partner} in an UNSPECIFIED half order —
// the prologue probe self-calibrates whatever order the HW produces.
static __device__ __forceinline__ void SWAP16(unsigned v, unsigned& x, unsigned& y) {
#if __has_builtin(__builtin_amdgcn_permlane16_swap)
    auto r = __builtin_amdgcn_permlane16_swap(v, v, false, false);
    x = (unsigned)r[0]; y = (unsigned)r[1];
#else
    x = v; y = (unsigned)__builtin_amdgcn_ds_swizzle((int)v, 0x401F);  // XOR16 (per 32-half)
#endif
}
// Exchange across the 32-lane boundary (lanes i <-> i^32).
static __device__ __forceinline__ void SWAP32(unsigned v, unsigned& x, unsigned& y) {
#if __has_builtin(__builtin_amdgcn_permlane32_swap)
    auto r = __builtin_amdgcn_permlane32_swap(v, v, false, false);
    x = (unsigned)r[0]; y = (unsigned)r[1];
#else
    const int l = (int)(threadIdx.x & 63);
    x = v; y = (unsigned)__builtin_amdgcn_ds_bpermute((l ^ 32) << 2, (int)v);
#endif
}

// All-gather butterfly: input x = one 16-bit payload per lane (low 16 bits).
// Output g[32] = all 64 lanes' payloads packed 2-per-reg, in a per-lane order
// that is fixed by HW semantics; g covers all 64 lanes for ANY direction /
// half-order semantics of the primitives (unions of distinct quads/rows/halves).
static __device__ __forceinline__ void bfly(unsigned x, unsigned g[32]) {
    const unsigned q  = DPPMOV<0xB1>(x);               // quad_perm [1,0,3,2]  (XOR1)
    const unsigned a0 = (x & 0xffffu) | (q << 16);
    const unsigned a1 = DPPMOV<0x4E>(a0);              // quad_perm [2,3,0,1]  (XOR2)
    const unsigned a2 = DPPMOV<0x124>(a0);             // row_ror:4
    const unsigned a3 = DPPMOV<0x124>(a1);
    const unsigned a4 = DPPMOV<0x128>(a0);             // row_ror:8
    const unsigned a5 = DPPMOV<0x128>(a1);
    const unsigned a6 = DPPMOV<0x128>(a2);
    const unsigned a7 = DPPMOV<0x128>(a3);
    unsigned b[16];
    SWAP16(a0, b[0],  b[1]);  SWAP16(a1, b[2],  b[3]);
    SWAP16(a2, b[4],  b[5]);  SWAP16(a3, b[6],  b[7]);
    SWAP16(a4, b[8],  b[9]);  SWAP16(a5, b[10], b[11]);
    SWAP16(a6, b[12], b[13]); SWAP16(a7, b[14], b[15]);
    #pragma unroll
    for (int k = 0; k < 16; ++k) SWAP32(b[k], g[2 * k], g[2 * k + 1]);
}

__global__ __launch_bounds__(64) void crf_nll_kernel(
    const float* __restrict__ logits,   // [N, T, C] f32
    const int*   __restrict__ lengths,  // [N] i32
    const int*   __restrict__ tags,     // [N, T] i32
    const float* __restrict__ trans,    // [C, C] f32
    float* __restrict__ out, int N)
{
    const int n    = blockIdx.x;
    if (n >= N) return;
    const int lane = threadIdx.x;   // class index i, 0..63

    const int len = lengths[n];               // in [1, T-1]
    const float* lg = logits + (size_t)n * TDIM * NCLS;
    const int*   tg = tags   + (size_t)n * TDIM;
    const float INV_C = 1.0f / (float)NCLS;

    // ---- preload all tags for this sample (gold-score tail) ----
    int tr8[PD];
    #pragma unroll
    for (int k = 0; k < PD; ++k) tr8[k] = tg[lane + NCLS * k];

    // ---- transition row `lane`: max + row-sum (linear pass, warms L1) ----
    float tmax = -3.0e38f, tsum = 0.f;
    #pragma unroll
    for (int j = 0; j < NCLS; j += 4) {
        const float4 v = *reinterpret_cast<const float4*>(&trans[lane * NCLS + j]);
        tmax = fmaxf(fmaxf(tmax, v.x), fmaxf(v.y, fmaxf(v.z, v.w)));
        tsum += (v.x + v.y) + (v.z + v.w);
    }
    float mT = tmax;
    #pragma unroll
    for (int o = 32; o; o >>= 1) mT = fmaxf(mT, __shfl_xor(mT, o));

    // ---- probe: discover this lane's butterfly ordering pi, then pack
    //      trow in exactly that order (self-calibrating vs HW semantics) ----
    unsigned pi[32];
    bfly((unsigned)lane, pi);
    h2 tp[32];
    #pragma unroll
    for (int k = 0; k < 32; ++k) {
        const int jl = (int)(pi[k] & 0xffffu);
        const int jh = (int)(pi[k] >> 16);
        const float tl = trans[lane * NCLS + jl];   // L1-hot (just streamed)
        const float th = trans[lane * NCLS + jh];
        h2 p;
        p.x = (_Float16)(__expf(tl - mT) * 0.015625f);
        p.y = (_Float16)(__expf(th - mT) * 0.015625f);
        tp[k] = p;
    }

    // first-step bits early so their gathers issue now
    const int   t0 = __shfl(tr8[0], 0);          // tags[0]
    const float rs = __shfl(tsum, t0);           // row-sum of T at row tags[0]
    const float first = lg[t0] + rs;

    // ---- exp-space recurrence (no LDS, no cross-lane reduce per step) ----
    // alpha_i(t) = B_t + ln f_i, B_t = t*(mT+ln64) + B_renorm (uniform, analytic)
    // f'_i = (sum_j expT[i,j] * f_j) * p_i,  p_i = exp(logit_t,i / 64)
    float f = 1.0f;
    float B = 0.0f;

    float lgr[PD];
    #pragma unroll
    for (int k = 0; k < PD; ++k) lgr[k] = lg[(size_t)k * NCLS + lane];

    const int nblk = len >> 3;
    const int tail = len & 7;

    #define CRF_STEP(PVAL)                                                     \
    {                                                                          \
        const unsigned hx =                                                    \
            (unsigned)__builtin_bit_cast(unsigned short, (_Float16)f);         \
        unsigned gg[32];                                                       \
        bfly(hx, gg);                                                          \
        float d[8];                                                            \
        _Pragma("unroll")                                                      \
        for (int k = 0; k < 8; ++k) d[k] = 0.f;                                \
        _Pragma("unroll")                                                      \
        for (int k = 0; k < 32; ++k) d[k & 7] = FDOT2(tp[k], BC_H2(gg[k]), d[k & 7]); \
        const float dot = (((d[0] + d[1]) + (d[2] + d[3])) +                   \
                           ((d[4] + d[5]) + (d[6] + d[7])));                   \
        f = dot * (PVAL);                                                      \
    }

    int t = 0;
    for (int b = 0; b < nblk; ++b) {
        #pragma unroll
        for (int k = 0; k < PD; ++k) {
            const float p = __expf(lgr[k] * INV_C);      // off critical path
            int nidx = t + k + PD; nidx = (nidx > TDIM - 1) ? (TDIM - 1) : nidx;
            lgr[k] = lg[(size_t)nidx * NCLS + lane];     // lands 8 steps out
            CRF_STEP(p);
        }
        t += PD;
        if ((b & 7) == 7) {            // periodic renorm: keep f in f32/f16 range
            float r = __builtin_bit_cast(float,
                          __builtin_amdgcn_readfirstlane(__builtin_bit_cast(int, f)));
            r = fmaxf(r, 1e-30f);
            f *= __builtin_amdgcn_rcpf(r);
            B += __logf(r);
        }
    }

    #pragma unroll
    for (int k = 0; k < PD - 1; ++k) {
        if (k < tail) {                 // uniform per block
            const float p = __expf(lgr[k] * INV_C);
            CRF_STEP(p);
        }
    }
    #undef CRF_STEP

    // ---- gold score: tags in registers; all gathers issue at once ----
    float g = 0.f;
    #pragma unroll
    for (int k = 0; k < PD; ++k) {
        const int m = 1 + lane + NCLS * k;
        if (m <= len) {
            const int rot  = __shfl(tr8[k], (lane + 1) & 63);        // tg[m], lane<63
            const int wrap = __shfl(tr8[(k + 1) & (PD - 1)], 0);     // tg[m], lane==63
            const int tm = (lane == 63) ? wrap : rot;
            const int tp_ = tr8[k];                                   // tg[m-1]
            g += trans[tm * NCLS + tp_] + lg[(size_t)m * NCLS + tm];
        }
    }

    // ---- combine: out = 64*B_len + sum_i(ln f_i - g_i) - first ----
    float v = __logf(f) - g;
    #pragma unroll
    for (int o = 32; o; o >>= 1) v += __shfl_xor(v, o);

    if (lane == 0) {
        const float Bt = (float)len * (mT + 4.1588830833596715f) + B; // ln(64)
        out[n] = 64.0f * Bt + v - first;
    }
}

extern "C" void kernel_launch(void* const* d_in, const int* in_sizes, int n_in,
                              void* d_out, int out_size, void* d_ws, size_t ws_size,
                              hipStream_t stream) {
    const float* logits  = (const float*)d_in[0];
    const int*   lengths = (const int*)  d_in[1];
    const int*   tags    = (const int*)  d_in[2];
    const float* trans   = (const float*)d_in[3];
    float* out = (float*)d_out;
    const int N = in_sizes[1];   // 512

    crf_nll_kernel<<<N, 64, 0, stream>>>(logits, lengths, tags, trans, out, N);
}